// Round 7
// baseline (1914.638 us; speedup 1.0000x reference)
//
#include <hip/hip_runtime.h>
#include <hip/hip_bf16.h>

#define B_   64
#define T_   2048
#define IN_  256
#define H_   128
#define G_   512          // 4*H
#define M_   (B_ * T_)    // 131072

typedef __bf16 bf16x8 __attribute__((ext_vector_type(8)));
typedef _Float16 f16x8 __attribute__((ext_vector_type(8)));
typedef float f32x4 __attribute__((ext_vector_type(4)));
typedef unsigned short u16x8 __attribute__((ext_vector_type(8)));

#define L2E_  1.442695041f

__device__ __forceinline__ unsigned short f2bf(float f) {   // RNE fp32->bf16
    unsigned u = __float_as_uint(f);
    return (unsigned short)((u + 0x7fffu + ((u >> 16) & 1u)) >> 16);
}
__device__ __forceinline__ float sigp(float x) {
    return __builtin_amdgcn_rcpf(1.f + __builtin_amdgcn_exp2f(-L2E_ * x));
}
__device__ __forceinline__ float tanhp(float x) {
    return fmaf(2.f, __builtin_amdgcn_rcpf(1.f + __builtin_amdgcn_exp2f(-2.f * L2E_ * x)), -1.f);
}

// ---------------------------------------------------------------------------
// K1: bf16 MFMA GEMM.  xp[dir][m][q*4+g] = x[m].w_ih[dir][g*128+q] + biases
// ---------------------------------------------------------------------------
__global__ __launch_bounds__(256) void gemm_in_mfma(
    const float* __restrict__ x,
    const float* __restrict__ w_f, const float* __restrict__ w_b,
    const float* __restrict__ bi_f, const float* __restrict__ bh_f,
    const float* __restrict__ bi_b, const float* __restrict__ bh_b,
    __hip_bfloat16* __restrict__ xp)
{
    const int nt  = blockIdx.x;          // 0..15
    const int m0  = blockIdx.y * 64;
    const int dir = nt >> 3;
    const int q0  = (nt & 7) * 16;
    const float* __restrict__ w  = dir ? w_b  : w_f;
    const float* __restrict__ bi = dir ? bi_b : bi_f;
    const float* __restrict__ bh = dir ? bh_b : bh_f;

    __shared__ alignas(16) unsigned short Asm[64 * 64];
    __shared__ alignas(16) unsigned short Bsm[64 * 64];
    __shared__ float bias_s[64];

    const int tid = threadIdx.x;
    const int wv  = tid >> 6;
    const int ln  = tid & 63;
    const int wr  = (wv >> 1) * 32;
    const int wc  = (wv & 1) * 32;
    const int l15 = ln & 15;
    const int l4  = ln >> 4;

#define STAGE_A(c2, k0) { int row = (c2) >> 3, kc = (c2) & 7; \
    const float4* sp = reinterpret_cast<const float4*>(x + (size_t)(m0 + row) * 256 + (k0) + kc * 8); \
    float4 fa = sp[0], fb = sp[1]; \
    u16x8 pk; pk[0]=f2bf(fa.x); pk[1]=f2bf(fa.y); pk[2]=f2bf(fa.z); pk[3]=f2bf(fa.w); \
    pk[4]=f2bf(fb.x); pk[5]=f2bf(fb.y); pk[6]=f2bf(fb.z); pk[7]=f2bf(fb.w); \
    *reinterpret_cast<u16x8*>(reinterpret_cast<char*>(Asm) + row * 128 + ((kc * 16) ^ ((row & 7) << 4))) = pk; }

#define STAGE_B(c2, k0) { int row = (c2) >> 3, kc = (c2) & 7; \
    int nglob = (row & 3) * 128 + q0 + (row >> 2); \
    const float4* sp = reinterpret_cast<const float4*>(w + (size_t)nglob * 256 + (k0) + kc * 8); \
    float4 fa = sp[0], fb = sp[1]; \
    u16x8 pk; pk[0]=f2bf(fa.x); pk[1]=f2bf(fa.y); pk[2]=f2bf(fa.z); pk[3]=f2bf(fa.w); \
    pk[4]=f2bf(fb.x); pk[5]=f2bf(fb.y); pk[6]=f2bf(fb.z); pk[7]=f2bf(fb.w); \
    *reinterpret_cast<u16x8*>(reinterpret_cast<char*>(Bsm) + row * 128 + ((kc * 16) ^ ((row & 7) << 4))) = pk; }

#define FRAG(BASE, rowe, kb) \
    __builtin_bit_cast(bf16x8, *reinterpret_cast<const uint4*>( \
        reinterpret_cast<const char*>(BASE) + (rowe) * 128 + ((kb) ^ (((rowe) & 7) << 4))))

    STAGE_A(tid, 0)  STAGE_A(tid + 256, 0)
    STAGE_B(tid, 0)  STAGE_B(tid + 256, 0)
    if (tid < 64) {
        int n = (tid & 3) * 128 + q0 + (tid >> 2);
        bias_s[tid] = bi[n] + bh[n];
    }
    __syncthreads();

    const float bv0 = bias_s[wc + l15];
    const float bv1 = bias_s[wc + 16 + l15];
    f32x4 acc00 = {bv0, bv0, bv0, bv0};
    f32x4 acc01 = {bv1, bv1, bv1, bv1};
    f32x4 acc10 = {bv0, bv0, bv0, bv0};
    f32x4 acc11 = {bv1, bv1, bv1, bv1};

    const int ra0 = wr + l15,      ra1 = wr + 16 + l15;
    const int rb0 = wc + l15,      rb1 = wc + 16 + l15;

    for (int kst = 0; kst < 4; ++kst) {
        if (kst) {
            __syncthreads();
            STAGE_A(tid, kst * 64)  STAGE_A(tid + 256, kst * 64)
            STAGE_B(tid, kst * 64)  STAGE_B(tid + 256, kst * 64)
            __syncthreads();
        }
        #pragma unroll
        for (int ks = 0; ks < 64; ks += 32) {
            int kb = ks * 2 + (l4 << 4);
            bf16x8 a0 = FRAG(Asm, ra0, kb);
            bf16x8 a1 = FRAG(Asm, ra1, kb);
            bf16x8 b0 = FRAG(Bsm, rb0, kb);
            bf16x8 b1 = FRAG(Bsm, rb1, kb);
            acc00 = __builtin_amdgcn_mfma_f32_16x16x32_bf16(a0, b0, acc00, 0, 0, 0);
            acc01 = __builtin_amdgcn_mfma_f32_16x16x32_bf16(a0, b1, acc01, 0, 0, 0);
            acc10 = __builtin_amdgcn_mfma_f32_16x16x32_bf16(a1, b0, acc10, 0, 0, 0);
            acc11 = __builtin_amdgcn_mfma_f32_16x16x32_bf16(a1, b1, acc11, 0, 0, 0);
        }
    }
    __syncthreads();

#define DWRITE(accv, mi, ni) { int row = wr + (mi) * 16 + l4 * 4; int col = wc + (ni) * 16 + l15; \
    Asm[(row + 0) * 64 + col] = f2bf(accv[0]); Asm[(row + 1) * 64 + col] = f2bf(accv[1]); \
    Asm[(row + 2) * 64 + col] = f2bf(accv[2]); Asm[(row + 3) * 64 + col] = f2bf(accv[3]); }
    DWRITE(acc00, 0, 0) DWRITE(acc01, 0, 1) DWRITE(acc10, 1, 0) DWRITE(acc11, 1, 1)
#undef DWRITE
    __syncthreads();

    #pragma unroll
    for (int p = 0; p < 2; ++p) {
        int c2 = tid + p * 256;
        int row = c2 >> 3, ch = c2 & 7;
        uint4 v = *reinterpret_cast<const uint4*>(reinterpret_cast<const char*>(Asm) + row * 128 + ch * 16);
        *reinterpret_cast<uint4*>(xp + ((size_t)dir * M_ + m0 + row) * G_ + q0 * 4 + ch * 8) = v;
    }
#undef STAGE_A
#undef STAGE_B
}

// ---------------------------------------------------------------------------
// K2: persistent recurrence on the MFMA pipe. 128 WGs=(dir,b); 512 thr.
// Wave wv owns gate-row tiles 4wv..4wv+3 (rows r=Q*4+g of W'); W' A-frags
// persist in 64 VGPRs. B operand = h broadcast into all 16 cols (lane loads
// h[8*l4..+7]); D col n is then the gate vector for every n, and regs 0..3
// of each lane = i,f,g,o of cell 4*nt+l4. acc is initialized from prefetched
// xp (input+bias term) -> no adds. Lane activates cell (l15&3); lanes l15<4
// write h to LDS (fp16) + global (bf16). One lgkm-only raw barrier per step.
// ---------------------------------------------------------------------------
__global__ __launch_bounds__(512, 2) void lstm_rec(
    const __hip_bfloat16* __restrict__ xp,   // [2][B][T][128][4] (r=Q*4+g)
    const float* __restrict__ w_hh_f,        // [G][H]
    const float* __restrict__ w_hh_b,
    __hip_bfloat16* __restrict__ hs)         // [B][T][2H]
{
    const int wg  = blockIdx.x;
    const int dir = wg >> 6;
    const int b   = wg & 63;
    const int tid = threadIdx.x;
    const int wv  = tid >> 6;
    const int l   = tid & 63;
    const int l15 = l & 15;
    const int l4  = l >> 4;
    const int nsel = l15 & 3;
    const float* __restrict__ w_hh = dir ? w_hh_b : w_hh_f;

    // ---- persistent A fragments: W'[16*(4wv+nt)+l15][32*kt + 8*l4 + i] ----
#define LDA(nt, kt) f16x8 W##nt##_##kt; { \
    int r = 16 * (4 * wv + (nt)) + l15; \
    const float* p = w_hh + (size_t)((r & 3) * 128 + (r >> 2)) * 128 + 32 * (kt) + 8 * l4; \
    float4 u0 = *reinterpret_cast<const float4*>(p); \
    float4 u1 = *reinterpret_cast<const float4*>(p + 4); \
    W##nt##_##kt[0] = (_Float16)u0.x; W##nt##_##kt[1] = (_Float16)u0.y; \
    W##nt##_##kt[2] = (_Float16)u0.z; W##nt##_##kt[3] = (_Float16)u0.w; \
    W##nt##_##kt[4] = (_Float16)u1.x; W##nt##_##kt[5] = (_Float16)u1.y; \
    W##nt##_##kt[6] = (_Float16)u1.z; W##nt##_##kt[7] = (_Float16)u1.w; }
    LDA(0,0) LDA(0,1) LDA(0,2) LDA(0,3)
    LDA(1,0) LDA(1,1) LDA(1,2) LDA(1,3)
    LDA(2,0) LDA(2,1) LDA(2,2) LDA(2,3)
    LDA(3,0) LDA(3,1) LDA(3,2) LDA(3,3)
#undef LDA

    __shared__ alignas(16) _Float16 hbuf[2][H_];
    if (tid < 2 * H_) (&hbuf[0][0])[tid] = (_Float16)0.f;
    __syncthreads();

    const unsigned short* __restrict__ xb =
        reinterpret_cast<const unsigned short*>(xp) + ((size_t)(dir * B_ + b)) * T_ * G_;
    const int Qsel = 16 * wv + 4 * nsel + l4;          // cell this lane activates
    __hip_bfloat16* __restrict__ ho =
        hs + (size_t)b * T_ * (2 * H_) + dir * H_ + Qsel;
    _Float16* const hw1 = &hbuf[1][Qsel];
    _Float16* const hw0 = &hbuf[0][Qsel];
    const bool writer = (l15 < 4);

    float c_own = 0.f;
    int t = dir ? (T_ - 1) : 0;
    const int dt = dir ? -1 : 1;

    const int b0 = 16 * (4 * wv + 0) + 4 * l4;
    const int b1 = 16 * (4 * wv + 1) + 4 * l4;
    const int b2 = 16 * (4 * wv + 2) + 4 * l4;
    const int b3 = 16 * (4 * wv + 3) + 4 * l4;

#define XPLD(sp, off) (*reinterpret_cast<const uint2*>( \
    xb + (size_t)(dir ? (T_ - 1 - (sp)) : (sp)) * G_ + (off)))

    uint2 cA0 = XPLD(0, b0), cA1 = XPLD(0, b1), cA2 = XPLD(0, b2), cA3 = XPLD(0, b3);
    uint2 cB0 = XPLD(1, b0), cB1 = XPLD(1, b1), cB2 = XPLD(1, b2), cB3 = XPLD(1, b3);
    uint2 cC0 = XPLD(2, b0), cC1 = XPLD(2, b1), cC2 = XPLD(2, b2), cC3 = XPLD(2, b3);
    uint2 cD0 = XPLD(3, b0), cD1 = XPLD(3, b1), cD2 = XPLD(3, b2), cD3 = XPLD(3, b3);

#define LOF(u) __uint_as_float((u) << 16)
#define HIF(u) __uint_as_float((u) & 0xffff0000u)
#define MFMA16(A, B, C) __builtin_amdgcn_mfma_f32_16x16x32_f16(A, B, C, 0, 0, 0)

#define STEP(par, X0, X1, X2, X3, HW) { \
    const char* hp = reinterpret_cast<const char*>(&hbuf[par][0]); \
    f16x8 hb0 = *reinterpret_cast<const f16x8*>(hp + l4 * 16); \
    f16x8 hb1 = *reinterpret_cast<const f16x8*>(hp + 64 + l4 * 16); \
    f16x8 hb2 = *reinterpret_cast<const f16x8*>(hp + 128 + l4 * 16); \
    f16x8 hb3 = *reinterpret_cast<const f16x8*>(hp + 192 + l4 * 16); \
    f32x4 a0, a1, a2, a3; \
    a0[0] = LOF(X0.x); a0[1] = HIF(X0.x); a0[2] = LOF(X0.y); a0[3] = HIF(X0.y); \
    a1[0] = LOF(X1.x); a1[1] = HIF(X1.x); a1[2] = LOF(X1.y); a1[3] = HIF(X1.y); \
    a2[0] = LOF(X2.x); a2[1] = HIF(X2.x); a2[2] = LOF(X2.y); a2[3] = HIF(X2.y); \
    a3[0] = LOF(X3.x); a3[1] = HIF(X3.x); a3[2] = LOF(X3.y); a3[3] = HIF(X3.y); \
    a0 = MFMA16(W0_0, hb0, a0); a1 = MFMA16(W1_0, hb0, a1); \
    a2 = MFMA16(W2_0, hb0, a2); a3 = MFMA16(W3_0, hb0, a3); \
    a0 = MFMA16(W0_1, hb1, a0); a1 = MFMA16(W1_1, hb1, a1); \
    a2 = MFMA16(W2_1, hb1, a2); a3 = MFMA16(W3_1, hb1, a3); \
    a0 = MFMA16(W0_2, hb2, a0); a1 = MFMA16(W1_2, hb2, a1); \
    a2 = MFMA16(W2_2, hb2, a2); a3 = MFMA16(W3_2, hb2, a3); \
    a0 = MFMA16(W0_3, hb3, a0); a1 = MFMA16(W1_3, hb3, a1); \
    a2 = MFMA16(W2_3, hb3, a2); a3 = MFMA16(W3_3, hb3, a3); \
    float gi = nsel == 0 ? a0[0] : nsel == 1 ? a1[0] : nsel == 2 ? a2[0] : a3[0]; \
    float gf = nsel == 0 ? a0[1] : nsel == 1 ? a1[1] : nsel == 2 ? a2[1] : a3[1]; \
    float gg = nsel == 0 ? a0[2] : nsel == 1 ? a1[2] : nsel == 2 ? a2[2] : a3[2]; \
    float go = nsel == 0 ? a0[3] : nsel == 1 ? a1[3] : nsel == 2 ? a2[3] : a3[3]; \
    float si = sigp(gi), sf = sigp(gf); \
    float tg = tanhp(gg), so = sigp(go); \
    c_own = fmaf(sf, c_own, si * tg); \
    float h = so * tanhp(c_own); \
    if (writer) { \
        *(HW) = (_Float16)h; \
        ho[(size_t)t * (2 * H_)] = __float2bfloat16(h); \
    } \
    asm volatile("s_waitcnt lgkmcnt(0)" ::: "memory"); \
    __builtin_amdgcn_s_barrier(); \
    t += dt; }

    for (int blk = 0; blk < T_ / 4; ++blk) {
        int base = blk * 4 + 4;
        int s0 = base     > T_ - 1 ? T_ - 1 : base;
        int s1 = base + 1 > T_ - 1 ? T_ - 1 : base + 1;
        int s2 = base + 2 > T_ - 1 ? T_ - 1 : base + 2;
        int s3 = base + 3 > T_ - 1 ? T_ - 1 : base + 3;
        uint2 nA0 = XPLD(s0, b0), nA1 = XPLD(s0, b1), nA2 = XPLD(s0, b2), nA3 = XPLD(s0, b3);
        uint2 nB0 = XPLD(s1, b0), nB1 = XPLD(s1, b1), nB2 = XPLD(s1, b2), nB3 = XPLD(s1, b3);
        uint2 nC0 = XPLD(s2, b0), nC1 = XPLD(s2, b1), nC2 = XPLD(s2, b2), nC3 = XPLD(s2, b3);
        uint2 nD0 = XPLD(s3, b0), nD1 = XPLD(s3, b1), nD2 = XPLD(s3, b2), nD3 = XPLD(s3, b3);

        STEP(0, cA0, cA1, cA2, cA3, hw1)
        STEP(1, cB0, cB1, cB2, cB3, hw0)
        STEP(0, cC0, cC1, cC2, cC3, hw1)
        STEP(1, cD0, cD1, cD2, cD3, hw0)

        cA0 = nA0; cA1 = nA1; cA2 = nA2; cA3 = nA3;
        cB0 = nB0; cB1 = nB1; cB2 = nB2; cB3 = nB3;
        cC0 = nC0; cC1 = nC1; cC2 = nC2; cC3 = nC3;
        cD0 = nD0; cD1 = nD1; cD2 = nD2; cD3 = nD3;
    }
#undef STEP
#undef MFMA16
#undef LOF
#undef HIF
#undef XPLD
}

// ---------------------------------------------------------------------------
// K3: bf16 MFMA mixer. out[m][n] = hs[m].mixer_w[n] + mb[n], fp32 out.
// ---------------------------------------------------------------------------
__global__ __launch_bounds__(256) void mixer_mfma(
    const __hip_bfloat16* __restrict__ hs,   // [M][256] bf16
    const float* __restrict__ mw,            // [256][256] fp32
    const float* __restrict__ mb,
    float* __restrict__ out)                 // [M][256] fp32
{
    const int n0 = blockIdx.x * 64;
    const int m0 = blockIdx.y * 64;

    __shared__ alignas(16) unsigned short Asm[64 * 64];
    __shared__ alignas(16) unsigned short Bsm[64 * 64];
    __shared__ alignas(16) float Dlds[64 * 64];
    __shared__ float bias_s[64];

    const int tid = threadIdx.x;
    const int wv  = tid >> 6;
    const int ln  = tid & 63;
    const int wr  = (wv >> 1) * 32;
    const int wc  = (wv & 1) * 32;
    const int l15 = ln & 15;
    const int l4  = ln >> 4;

#define STAGE_A3(c2, k0) { int row = (c2) >> 3, kc = (c2) & 7; \
    uint4 v = *reinterpret_cast<const uint4*>(hs + (size_t)(m0 + row) * 256 + (k0) + kc * 8); \
    *reinterpret_cast<uint4*>(reinterpret_cast<char*>(Asm) + row * 128 + ((kc * 16) ^ ((row & 7) << 4))) = v; }
#define STAGE_B3(c2, k0) { int row = (c2) >> 3, kc = (c2) & 7; \
    const float4* sp = reinterpret_cast<const float4*>(mw + (size_t)(n0 + row) * 256 + (k0) + kc * 8); \
    float4 fa = sp[0], fb = sp[1]; \
    u16x8 pk; pk[0]=f2bf(fa.x); pk[1]=f2bf(fa.y); pk[2]=f2bf(fa.z); pk[3]=f2bf(fa.w); \
    pk[4]=f2bf(fb.x); pk[5]=f2bf(fb.y); pk[6]=f2bf(fb.z); pk[7]=f2bf(fb.w); \
    *reinterpret_cast<u16x8*>(reinterpret_cast<char*>(Bsm) + row * 128 + ((kc * 16) ^ ((row & 7) << 4))) = pk; }

    STAGE_A3(tid, 0)  STAGE_A3(tid + 256, 0)
    STAGE_B3(tid, 0)  STAGE_B3(tid + 256, 0)
    if (tid < 64) bias_s[tid] = mb[n0 + tid];
    __syncthreads();

    const float bv0 = bias_s[wc + l15];
    const float bv1 = bias_s[wc + 16 + l15];
    f32x4 acc00 = {bv0, bv0, bv0, bv0};
    f32x4 acc01 = {bv1, bv1, bv1, bv1};
    f32x4 acc10 = {bv0, bv0, bv0, bv0};
    f32x4 acc11 = {bv1, bv1, bv1, bv1};

    const int ra0 = wr + l15,      ra1 = wr + 16 + l15;
    const int rb0 = wc + l15,      rb1 = wc + 16 + l15;

    for (int kst = 0; kst < 4; ++kst) {
        if (kst) {
            __syncthreads();
            STAGE_A3(tid, kst * 64)  STAGE_A3(tid + 256, kst * 64)
            STAGE_B3(tid, kst * 64)  STAGE_B3(tid + 256, kst * 64)
            __syncthreads();
        }
        #pragma unroll
        for (int ks = 0; ks < 64; ks += 32) {
            int kb = ks * 2 + (l4 << 4);
            bf16x8 a0 = FRAG(Asm, ra0, kb);
            bf16x8 a1 = FRAG(Asm, ra1, kb);
            bf16x8 b0 = FRAG(Bsm, rb0, kb);
            bf16x8 b1 = FRAG(Bsm, rb1, kb);
            acc00 = __builtin_amdgcn_mfma_f32_16x16x32_bf16(a0, b0, acc00, 0, 0, 0);
            acc01 = __builtin_amdgcn_mfma_f32_16x16x32_bf16(a0, b1, acc01, 0, 0, 0);
            acc10 = __builtin_amdgcn_mfma_f32_16x16x32_bf16(a1, b0, acc10, 0, 0, 0);
            acc11 = __builtin_amdgcn_mfma_f32_16x16x32_bf16(a1, b1, acc11, 0, 0, 0);
        }
    }
    __syncthreads();

#define DWRITE3(accv, mi, ni) { int row = wr + (mi) * 16 + l4 * 4; int col = wc + (ni) * 16 + l15; \
    Dlds[(row + 0) * 64 + col] = accv[0]; Dlds[(row + 1) * 64 + col] = accv[1]; \
    Dlds[(row + 2) * 64 + col] = accv[2]; Dlds[(row + 3) * 64 + col] = accv[3]; }
    DWRITE3(acc00, 0, 0) DWRITE3(acc01, 0, 1) DWRITE3(acc10, 1, 0) DWRITE3(acc11, 1, 1)
#undef DWRITE3
    __syncthreads();

    #pragma unroll
    for (int p = 0; p < 4; ++p) {
        int c2 = tid + p * 256;
        int row = c2 >> 4, ch = c2 & 15;
        float4 v = *reinterpret_cast<const float4*>(Dlds + row * 64 + ch * 4);
        *reinterpret_cast<float4*>(out + (size_t)(m0 + row) * 256 + n0 + ch * 4) = v;
    }
#undef STAGE_A3
#undef STAGE_B3
#undef FRAG
}

// ---------------------------------------------------------------------------
extern "C" void kernel_launch(void* const* d_in, const int* in_sizes, int n_in,
                              void* d_out, int out_size, void* d_ws, size_t ws_size,
                              hipStream_t stream) {
    const float* x       = (const float*)d_in[0];
    const float* w_ih_f  = (const float*)d_in[1];
    const float* w_hh_f  = (const float*)d_in[2];
    const float* b_ih_f  = (const float*)d_in[3];
    const float* b_hh_f  = (const float*)d_in[4];
    const float* w_ih_b  = (const float*)d_in[5];
    const float* w_hh_b  = (const float*)d_in[6];
    const float* b_ih_b  = (const float*)d_in[7];
    const float* b_hh_b  = (const float*)d_in[8];
    const float* mixer_w = (const float*)d_in[9];
    const float* mixer_b = (const float*)d_in[10];
    float* out = (float*)d_out;

    const size_t xp_bytes = (size_t)2 * M_ * G_ * sizeof(__hip_bfloat16); // 256 MiB
    const size_t hs_bytes = (size_t)M_ * 2 * H_ * sizeof(__hip_bfloat16); //  64 MiB
    if (ws_size < xp_bytes + hs_bytes) return;

    __hip_bfloat16* xp = (__hip_bfloat16*)d_ws;
    __hip_bfloat16* hs = (__hip_bfloat16*)((char*)d_ws + xp_bytes);

    gemm_in_mfma<<<dim3(16, M_ / 64), 256, 0, stream>>>(
        x, w_ih_f, w_ih_b, b_ih_f, b_hh_f, b_ih_b, b_hh_b, xp);
    lstm_rec<<<128, 512, 0, stream>>>(xp, w_hh_f, w_hh_b, hs);
    mixer_mfma<<<dim3(4, M_ / 64), 256, 0, stream>>>(
        hs, mixer_w, mixer_b, out);
}